// Round 8
// baseline (147.998 us; speedup 1.0000x reference)
//
#include <hip/hip_runtime.h>

#define B_ 2
#define S_ 2048
#define DM 1024
#define NH 16
#define DK 64

using bf16x8  = __attribute__((ext_vector_type(8)))  short;
using f32x4   = __attribute__((ext_vector_type(4)))  float;
using f32x16  = __attribute__((ext_vector_type(16))) float;

__device__ __forceinline__ float bf2f(short v){
  unsigned u = ((unsigned)(unsigned short)v) << 16;
  union { unsigned u; float f; } c; c.u = u; return c.f;
}
__device__ __forceinline__ short f2bf(float f){
  union { float f; unsigned u; } c; c.f = f;
  unsigned u = c.u + 0x7FFFu + ((c.u >> 16) & 1u);
  return (short)(u >> 16);
}
// pack two f32 -> two bf16 (truncation) in one v_perm_b32
__device__ __forceinline__ unsigned packbf(float lo, float hi){
  union { float f; unsigned u; } a, b; a.f = lo; b.f = hi;
  return __builtin_amdgcn_perm(b.u, a.u, 0x07060302u);
}
// rounded pack (epilogue only)
__device__ __forceinline__ unsigned pack2(float a, float b){
  return (unsigned)(unsigned short)f2bf(a) | ((unsigned)(unsigned short)f2bf(b) << 16);
}
__device__ __forceinline__ void gload16(const void* g, void* l){
  __builtin_amdgcn_global_load_lds(
    (const __attribute__((address_space(1))) unsigned*)g,
    (__attribute__((address_space(3))) unsigned*)l, 16, 0, 0);
}
__device__ __forceinline__ f32x16 mfma32(bf16x8 a, bf16x8 b, f32x16 c){
  return __builtin_amdgcn_mfma_f32_32x32x16_bf16(a, b, c, 0, 0, 0);
}

// ---------------- RoPE table: [b*s][64] = cos[32] | sin[32] ----------------
__global__ void rope_table(const int* __restrict__ pos, float* __restrict__ tab){
  int idx = blockIdx.x * blockDim.x + threadIdx.x;
  if (idx >= B_ * S_ * 32) return;
  int j = idx & 31, bs = idx >> 5;
  float p = (float)pos[bs];
  float inv = powf(10000.0f, -(float)(2 * j) / 64.0f);
  float ang = p * inv;
  tab[(size_t)bs * 64 + j]      = cosf(ang);
  tab[(size_t)bs * 64 + 32 + j] = sinf(ang);
}

// ---------------- all fp32 -> bf16 casts in one kernel ----------------
__global__ void cast_all(const float* __restrict__ x, const float* __restrict__ wq,
                         const float* __restrict__ wk, const float* __restrict__ wv,
                         const float* __restrict__ wo,
                         short* __restrict__ xb, short* __restrict__ wqkv,
                         short* __restrict__ wob){
  int i = blockIdx.x * blockDim.x + threadIdx.x;   // float4 index, total 2M
  const float4* src; short4* dst;
  if (i < (1 << 20)){
    src = (const float4*)x + i; dst = (short4*)xb + i;
  } else {
    int j = i - (1 << 20);
    int seg = j >> 18, off = j & ((1 << 18) - 1);
    const float* sp = seg == 0 ? wq : seg == 1 ? wk : seg == 2 ? wv : wo;
    short* dp = seg < 3 ? wqkv + ((size_t)seg << 20) : wob;
    src = (const float4*)sp + off; dst = (short4*)dp + off;
  }
  float4 v = *src;
  short4 o; o.x = f2bf(v.x); o.y = f2bf(v.y); o.z = f2bf(v.z); o.w = f2bf(v.w);
  *dst = o;
}

// ---------------- 8-wave bf16 GEMM: C[M][N] = A[M][K] * B[N][K]^T, 128x128 tile, per-wave 64x32 ----------------
template<typename OutT>
__launch_bounds__(512)
__global__ void gemm_bt8(const short* __restrict__ A, const short* __restrict__ Bm,
                         OutT* __restrict__ C, int M, int N, int K){
  __shared__ short As[128 * 32];
  __shared__ short Bs[128 * 32];
  const int tid = threadIdx.x;
  const int l = tid & 63, w = tid >> 6;
  const int lr = l & 15, lg = l >> 4;
  const int wr = w >> 2, wc = w & 3;
  const int nwg = gridDim.x * gridDim.y;
  const int wg  = blockIdx.y * gridDim.x + blockIdx.x;
  const int sw  = (wg & 7) * (nwg >> 3) + (wg >> 3);
  const int bn  = sw % gridDim.x, bm = sw / gridDim.x;
  const short* Ab = A + (size_t)bm * 128 * K;
  const short* Bb = Bm + (size_t)bn * 128 * K;
  f32x4 acc[4][2];
  #pragma unroll
  for (int m = 0; m < 4; ++m)
    #pragma unroll
    for (int n = 0; n < 2; ++n) acc[m][n] = (f32x4){0.f, 0.f, 0.f, 0.f};
  const int r0 = tid >> 2, q4 = tid & 3;   // [128 rows][4 x 16B chunks], 512 thr
  for (int kt = 0; kt < K; kt += 32){
    gload16(Ab + (size_t)r0 * K + kt + q4 * 8, As + tid * 8);
    gload16(Bb + (size_t)r0 * K + kt + q4 * 8, Bs + tid * 8);
    __syncthreads();
    bf16x8 a[4], bfr[2];
    #pragma unroll
    for (int m = 0; m < 4; ++m)
      a[m] = *(const bf16x8*)(As + (wr * 64 + m * 16 + lr) * 32 + lg * 8);
    #pragma unroll
    for (int n = 0; n < 2; ++n)
      bfr[n] = *(const bf16x8*)(Bs + (wc * 32 + n * 16 + lr) * 32 + lg * 8);
    #pragma unroll
    for (int m = 0; m < 4; ++m)
      #pragma unroll
      for (int n = 0; n < 2; ++n)
        acc[m][n] = __builtin_amdgcn_mfma_f32_16x16x32_bf16(a[m], bfr[n], acc[m][n], 0, 0, 0);
    __syncthreads();
  }
  #pragma unroll
  for (int m = 0; m < 4; ++m)
    #pragma unroll
    for (int n = 0; n < 2; ++n)
      #pragma unroll
      for (int j = 0; j < 4; ++j){
        int row = bm * 128 + wr * 64 + m * 16 + lg * 4 + j;
        int col = bn * 128 + wc * 32 + n * 16 + lr;
        float v = acc[m][n][j];
        if constexpr (__is_same(OutT, short)) C[(size_t)row * N + col] = f2bf(v);
        else                                  C[(size_t)row * N + col] = v;
      }
}

// ---------------- RoPE + reshape: qkv[m][3072] -> Q/K [b,h,s,d] bf16; Q scaled by 1/8 ----------------
__global__ void rope_reshape(const short* __restrict__ qkv, const float* __restrict__ tab,
                             short* __restrict__ Qr, short* __restrict__ Kr){
  int idx = blockIdx.x * blockDim.x + threadIdx.x;   // 0 .. 2*2M-1 pairs
  int which = idx >> 21;                             // 0 = Q, 1 = K
  int p = idx & ((1 << 21) - 1);
  int dp = p & 31;
  int h  = (p >> 5) & 15;
  int bs = p >> 9;                                   // b*2048 + s
  const short* src = qkv + (size_t)bs * 3072 + which * 1024 + h * 64 + dp * 2;
  int pk = *(const int*)src;
  float e = bf2f((short)(pk & 0xFFFF));
  float o = bf2f((short)((unsigned)pk >> 16));
  const float* tb = tab + (size_t)bs * 64;
  float c = tb[dp], s = tb[32 + dp];
  float re = e * c - o * s;
  float ro = e * s + o * c;
  if (which == 0){ re *= 0.125f; ro *= 0.125f; }     // fold 1/sqrt(64) into Q
  unsigned pack = (unsigned)(unsigned short)f2bf(re) | ((unsigned)(unsigned short)f2bf(ro) << 16);
  int b = bs >> 11, si = bs & 2047;
  int* dstbase = (int*)(which ? Kr : Qr);
  dstbase[((size_t)(b * NH + h) * S_ + si) * 32 + dp] = pack;
}

// ---------------- V transpose: qkv V-part [b,s,h,d] -> Vt [b,h,d,s] bf16 ----------------
__global__ void vtrans(const short* __restrict__ qkv, short* __restrict__ Vt){
  __shared__ short t[64][72];
  const int tid = threadIdx.x;
  const int st = blockIdx.x, bh = blockIdx.y;
  const int b = bh >> 4, h = bh & 15;
  #pragma unroll
  for (int i = 0; i < 2; ++i){
    int c = tid + 256 * i;
    int sl = c >> 3, d8 = c & 7;
    const short* src = qkv + ((size_t)b * S_ + st * 64 + sl) * 3072 + 2048 + h * 64 + d8 * 8;
    *(bf16x8*)(&t[sl][d8 * 8]) = *(const bf16x8*)src;
  }
  __syncthreads();
  #pragma unroll
  for (int i = 0; i < 2; ++i){
    int c = tid + 256 * i;
    int dl = c >> 3, s8 = c & 7;
    bf16x8 v;
    #pragma unroll
    for (int jj = 0; jj < 8; ++jj) v[jj] = t[s8 * 8 + jj][dl];
    short* dst = Vt + ((size_t)bh * DK + dl) * S_ + st * 64 + s8 * 8;
    *(bf16x8*)dst = v;
  }
}

// ---------------- 32x32-fragment tile step: swapped QK^T, all-register softmax and P ----------------
// Ks/Vs XOR-swizzled [64 rows][8 x 16B chunks]: global chunk c of row r at slot c ^ (r&7).
// Lane (l31,hi) owns q-row l31 jointly with lane^32. C-layout: col=lane&31, row=(reg&3)+8(reg>>2)+4hi.
__device__ __forceinline__ void attn_step32(
    const bf16x8 (&qb)[4], f32x16& acc0, f32x16& acc1,
    float& mrow, float& lsum,
    const short* Ksb, const short* Vsb,
    int diagmask, int l31, int hi, int wl){
  // QK^T: z[t2] = S^T[k = t2*32 + crow(reg,hi)][q' = l31]
  f32x16 z0, z1;
  #pragma unroll
  for (int i = 0; i < 16; ++i){ z0[i] = 0.f; z1[i] = 0.f; }
  const int rsw = l31 & 7;              // row-swizzle term (rows r and r+32 share it)
  #pragma unroll
  for (int ds = 0; ds < 4; ++ds){
    const int slot = (ds * 2 + hi) ^ rsw;
    bf16x8 k0 = *(const bf16x8*)(Ksb + l31 * 64        + slot * 8);
    bf16x8 k1 = *(const bf16x8*)(Ksb + (32 + l31) * 64 + slot * 8);
    z0 = mfma32(k0, qb[ds], z0);
    z1 = mfma32(k1, qb[ds], z1);
  }
  float sv[32];
  #pragma unroll
  for (int r = 0; r < 16; ++r){ sv[r] = z0[r]; sv[16 + r] = z1[r]; }
  if (diagmask){
    const int qloc = wl * 32 + l31;
    #pragma unroll
    for (int t2 = 0; t2 < 2; ++t2)
      #pragma unroll
      for (int r = 0; r < 16; ++r){
        const int kloc = t2 * 32 + (r & 3) + 8 * (r >> 2) + 4 * hi;
        if (kloc > qloc) sv[t2 * 16 + r] = -1e30f;
      }
  }
  float lm = sv[0];
  #pragma unroll
  for (int i = 1; i < 32; ++i) lm = fmaxf(lm, sv[i]);
  lm = fmaxf(lm, __shfl_xor(lm, 32));
  // defer-max (T13)
  if (!__all(lm <= mrow + 8.f)){
    const float mnew = fmaxf(mrow, lm);
    const float corr = __expf(mrow - mnew);
    mrow = mnew; lsum *= corr;
    #pragma unroll
    for (int i = 0; i < 16; ++i){ acc0[i] *= corr; acc1[i] *= corr; }
  }
  float ps = 0.f;
  #pragma unroll
  for (int i = 0; i < 32; ++i){
    const float e = __expf(sv[i] - mrow);
    sv[i] = e; ps += e;
  }
  ps += __shfl_xor(ps, 32);
  lsum += ps;
  // own packed pairs per 8-wide k-block bb: sv index (bb>>2)*16 + (bb&3)*4 + t  ->  k = 8*bb + 4*hi + t
  unsigned p0[8], p1[8];
  #pragma unroll
  for (int bb = 0; bb < 8; ++bb){
    const int i0 = (bb >> 2) * 16 + (bb & 3) * 4;
    p0[bb] = packbf(sv[i0 + 0], sv[i0 + 1]);
    p1[bb] = packbf(sv[i0 + 2], sv[i0 + 3]);
  }
  // PV: per k-slice ks, exchange the missing half-block with lane^32 and feed B-frag directly
  #pragma unroll
  for (int ks = 0; ks < 4; ++ks){
    const unsigned s0 = hi ? p0[2 * ks] : p0[2 * ks + 1];   // send block 2ks + (hi^1)
    const unsigned s1 = hi ? p1[2 * ks] : p1[2 * ks + 1];
    const unsigned r0e = __shfl_xor(s0, 32);
    const unsigned r1e = __shfl_xor(s1, 32);
    union { unsigned u[4]; bf16x8 v; } pf;
    pf.u[0] = hi ? r0e          : p0[2 * ks];
    pf.u[1] = hi ? r1e          : p1[2 * ks];
    pf.u[2] = hi ? p0[2 * ks+1] : r0e;
    pf.u[3] = hi ? p1[2 * ks+1] : r1e;
    const int slot = (ks * 2 + hi) ^ rsw;
    bf16x8 v0 = *(const bf16x8*)(Vsb + l31 * 64        + slot * 8);
    bf16x8 v1 = *(const bf16x8*)(Vsb + (32 + l31) * 64 + slot * 8);
    acc0 = mfma32(v0, pf.v, acc0);
    acc1 = mfma32(v1, pf.v, acc1);
  }
}

// ---------------- flash attention: paired Q-tiles (qt, 31-qt), wave-pair per tile, 32x32 MFMA ----------------
__launch_bounds__(256)
__global__ void attn_kernel(const short* __restrict__ Qr, const short* __restrict__ Kr,
                            const short* __restrict__ Vt, short* __restrict__ AO){
  __shared__ short Ks[2][64 * 64];
  __shared__ short Vs[2][64 * 64];   // [d][kk]
  const int tid = threadIdx.x;
  const int l = tid & 63, w = tid >> 6;
  const int l31 = l & 31, hi = l >> 5;
  const int wl = w & 1, wgp = w >> 1;          // wave-pair: wgp 0 -> t1, 1 -> t0
  const int qp = blockIdx.x, h = blockIdx.y, b = blockIdx.z;
  const int t0 = qp, t1 = 31 - qp;
  const int myqt = wgp ? t0 : t1;
  const int bh = b * NH + h;
  const short* Qp = Qr + (size_t)bh * S_ * DK;
  const short* Kp = Kr + (size_t)bh * S_ * DK;
  const short* Vp = Vt + (size_t)bh * DK * S_;

  bf16x8 qb[4];
  {
    const short* qrow = Qp + (size_t)(myqt * 64 + wl * 32 + l31) * DK;
    #pragma unroll
    for (int ds = 0; ds < 4; ++ds) qb[ds] = *(const bf16x8*)(qrow + (ds * 2 + hi) * 8);
  }
  f32x16 acc0, acc1;
  #pragma unroll
  for (int i = 0; i < 16; ++i){ acc0[i] = 0.f; acc1[i] = 0.f; }
  float ms = -1e30f, ls = 0.f;

  const int r0 = tid >> 3, c8 = tid & 7;       // staging: [64 rows][8 x 16B chunks], 2 loads each
  const int sc = c8 ^ (r0 & 7);                // pre-swizzled source chunk (rule #21)
  // prologue: stage tile 0 into buffer 0
  {
    const short* kb = Kp + (size_t)r0 * DK + sc * 8;
    gload16(kb,           &Ks[0][tid * 8]);
    gload16(kb + 32 * DK, &Ks[0][(tid + 256) * 8]);
    const short* vb = Vp + (size_t)r0 * S_ + sc * 8;
    gload16(vb,           &Vs[0][tid * 8]);
    gload16(vb + 32 * S_, &Vs[0][(tid + 256) * 8]);
  }
  int cur = 0;
  for (int kt = 0; kt <= t1; ++kt){
    __syncthreads();   // buf[cur] staged; all waves done reading buf[cur^1]
    if (kt < t1){
      const short* kb = Kp + (size_t)((kt + 1) * 64 + r0) * DK + sc * 8;
      gload16(kb,           &Ks[cur ^ 1][tid * 8]);
      gload16(kb + 32 * DK, &Ks[cur ^ 1][(tid + 256) * 8]);
      const short* vb = Vp + (size_t)r0 * S_ + (kt + 1) * 64 + sc * 8;
      gload16(vb,           &Vs[cur ^ 1][tid * 8]);
      gload16(vb + 32 * S_, &Vs[cur ^ 1][(tid + 256) * 8]);
    }
    if (kt <= myqt)
      attn_step32(qb, acc0, acc1, ms, ls, Ks[cur], Vs[cur], kt == myqt, l31, hi, wl);
    cur ^= 1;
  }
  const float li = 1.f / ls;
  const int qrow = myqt * 64 + wl * 32 + l31;
  short* dst = AO + ((size_t)b * S_ + qrow) * DM + h * 64;
  #pragma unroll
  for (int g = 0; g < 4; ++g){
    {
      uint2 st;
      st.x = pack2(acc0[g * 4 + 0] * li, acc0[g * 4 + 1] * li);
      st.y = pack2(acc0[g * 4 + 2] * li, acc0[g * 4 + 3] * li);
      *(uint2*)(dst + 8 * g + 4 * hi) = st;
    }
    {
      uint2 st;
      st.x = pack2(acc1[g * 4 + 0] * li, acc1[g * 4 + 1] * li);
      st.y = pack2(acc1[g * 4 + 2] * li, acc1[g * 4 + 3] * li);
      *(uint2*)(dst + 32 + 8 * g + 4 * hi) = st;
    }
  }
}

extern "C" void kernel_launch(void* const* d_in, const int* in_sizes, int n_in,
                              void* d_out, int out_size, void* d_ws, size_t ws_size,
                              hipStream_t stream){
  const float* x  = (const float*)d_in[0];
  const float* wq = (const float*)d_in[1];
  const float* wk = (const float*)d_in[2];
  const float* wv = (const float*)d_in[3];
  const float* wo = (const float*)d_in[4];
  const int*  pos = (const int*)d_in[5];

  char* ws = (char*)d_ws;
  short* xb   = (short*)(ws + 0);                       // 8 MB  [4096][1024] bf16 x
  short* wqkv = (short*)(ws + ((size_t)8  << 20));      // 6 MB  [3072][1024] bf16 (wq|wk|wv)
  short* wob  = (short*)(ws + ((size_t)14 << 20));      // 2 MB  [1024][1024]
  short* qkv  = (short*)(ws + ((size_t)16 << 20));      // 24 MB [4096][3072]
  short* Qr   = (short*)(ws + ((size_t)40 << 20));      // 8 MB  [b,h,s,d]
  short* Kr   = (short*)(ws + ((size_t)48 << 20));      // 8 MB  [b,h,s,d]
  short* Vt   = (short*)(ws + ((size_t)56 << 20));      // 8 MB  [b,h,d,s]
  float* tab  = (float*)(ws + ((size_t)64 << 20));      // 1 MB  rope table
  short* AO   = xb;                                     // reuse xb (dead after GEMM1)
  float* out  = (float*)d_out;

  rope_table<<<dim3((B_ * S_ * 32 + 255) / 256), dim3(256), 0, stream>>>(pos, tab);
  cast_all<<<dim3(8192), dim3(256), 0, stream>>>(x, wq, wk, wv, wo, xb, wqkv, wob);
  gemm_bt8<short><<<dim3(24, 32), dim3(512), 0, stream>>>(xb, wqkv, qkv, 4096, 3072, 1024);
  rope_reshape<<<dim3(16384), dim3(256), 0, stream>>>(qkv, tab, Qr, Kr);
  vtrans<<<dim3(32, 32), dim3(256), 0, stream>>>(qkv, Vt);
  attn_kernel<<<dim3(16, NH, B_), dim3(256), 0, stream>>>(Qr, Kr, Vt, AO);
  gemm_bt8<float><<<dim3(8, 32), dim3(512), 0, stream>>>(AO, wob, out, 4096, 1024, 1024);
}

// Round 9
// 130.902 us; speedup vs baseline: 1.1306x; 1.1306x over previous
//
#include <hip/hip_runtime.h>

#define B_ 2
#define S_ 2048
#define DM 1024
#define NH 16
#define DK 64

using bf16x8  = __attribute__((ext_vector_type(8)))  short;
using f32x4   = __attribute__((ext_vector_type(4)))  float;

__device__ __forceinline__ float bf2f(short v){
  unsigned u = ((unsigned)(unsigned short)v) << 16;
  union { unsigned u; float f; } c; c.u = u; return c.f;
}
__device__ __forceinline__ short f2bf(float f){
  union { float f; unsigned u; } c; c.f = f;
  unsigned u = c.u + 0x7FFFu + ((c.u >> 16) & 1u);
  return (short)(u >> 16);
}
// pack two f32 -> two bf16 (truncation) in one v_perm_b32
__device__ __forceinline__ unsigned packbf(float lo, float hi){
  union { float f; unsigned u; } a, b; a.f = lo; b.f = hi;
  return __builtin_amdgcn_perm(b.u, a.u, 0x07060302u);
}
__device__ __forceinline__ void gload16(const void* g, void* l){
  __builtin_amdgcn_global_load_lds(
    (const __attribute__((address_space(1))) unsigned*)g,
    (__attribute__((address_space(3))) unsigned*)l, 16, 0, 0);
}

// ---------------- RoPE table: [token][64] = cos[32] | sin[32] ----------------
__global__ void rope_table(const int* __restrict__ pos, float* __restrict__ tab){
  int idx = blockIdx.x * blockDim.x + threadIdx.x;
  if (idx >= B_ * S_ * 32) return;
  int j = idx & 31, bs = idx >> 5;
  float p = (float)pos[bs];
  float inv = powf(10000.0f, -(float)(2 * j) / 64.0f);
  float ang = p * inv;
  tab[(size_t)bs * 64 + j]      = cosf(ang);
  tab[(size_t)bs * 64 + 32 + j] = sinf(ang);
}

// ---------------- all fp32 -> bf16 casts in one kernel ----------------
__global__ void cast_all(const float* __restrict__ x, const float* __restrict__ wq,
                         const float* __restrict__ wk, const float* __restrict__ wv,
                         const float* __restrict__ wo,
                         short* __restrict__ xb, short* __restrict__ wqkv,
                         short* __restrict__ wob){
  int i = blockIdx.x * blockDim.x + threadIdx.x;   // float4 index, total 2M
  const float4* src; short4* dst;
  if (i < (1 << 20)){
    src = (const float4*)x + i; dst = (short4*)xb + i;
  } else {
    int j = i - (1 << 20);
    int seg = j >> 18, off = j & ((1 << 18) - 1);
    const float* sp = seg == 0 ? wq : seg == 1 ? wk : seg == 2 ? wv : wo;
    short* dp = seg < 3 ? wqkv + ((size_t)seg << 20) : wob;
    src = (const float4*)sp + off; dst = (short4*)dp + off;
  }
  float4 v = *src;
  short4 o; o.x = f2bf(v.x); o.y = f2bf(v.y); o.z = f2bf(v.z); o.w = f2bf(v.w);
  *dst = o;
}

// ---------------- GEMM1 (8-wave) with fused RoPE epilogue ----------------
// C[row=token][col=e of 3072]; col<1024 -> Q (rope, *0.125), <2048 -> K (rope), else V raw.
__launch_bounds__(512)
__global__ void gemm_qkv(const short* __restrict__ A, const short* __restrict__ Bm,
                         const float* __restrict__ tab,
                         short* __restrict__ Qr, short* __restrict__ Kr,
                         short* __restrict__ Vq, int K){
  __shared__ short As[128 * 32];
  __shared__ short Bs[128 * 32];
  const int tid = threadIdx.x;
  const int l = tid & 63, w = tid >> 6;
  const int lr = l & 15, lg = l >> 4;
  const int wr = w >> 2, wc = w & 3;
  const int nwg = gridDim.x * gridDim.y;
  const int wg  = blockIdx.y * gridDim.x + blockIdx.x;
  const int sw  = (wg & 7) * (nwg >> 3) + (wg >> 3);
  const int bn  = sw % gridDim.x, bm = sw / gridDim.x;
  const short* Ab = A + (size_t)bm * 128 * K;
  const short* Bb = Bm + (size_t)bn * 128 * K;
  f32x4 acc[4][2];
  #pragma unroll
  for (int m = 0; m < 4; ++m)
    #pragma unroll
    for (int n = 0; n < 2; ++n) acc[m][n] = (f32x4){0.f, 0.f, 0.f, 0.f};
  const int r0 = tid >> 2, q4 = tid & 3;
  for (int kt = 0; kt < K; kt += 32){
    gload16(Ab + (size_t)r0 * K + kt + q4 * 8, As + tid * 8);
    gload16(Bb + (size_t)r0 * K + kt + q4 * 8, Bs + tid * 8);
    __syncthreads();
    bf16x8 a[4], bfr[2];
    #pragma unroll
    for (int m = 0; m < 4; ++m)
      a[m] = *(const bf16x8*)(As + (wr * 64 + m * 16 + lr) * 32 + lg * 8);
    #pragma unroll
    for (int n = 0; n < 2; ++n)
      bfr[n] = *(const bf16x8*)(Bs + (wc * 32 + n * 16 + lr) * 32 + lg * 8);
    #pragma unroll
    for (int m = 0; m < 4; ++m)
      #pragma unroll
      for (int n = 0; n < 2; ++n)
        acc[m][n] = __builtin_amdgcn_mfma_f32_16x16x32_bf16(a[m], bfr[n], acc[m][n], 0, 0, 0);
    __syncthreads();
  }
  #pragma unroll
  for (int m = 0; m < 4; ++m)
    #pragma unroll
    for (int n = 0; n < 2; ++n){
      const int col = bn * 128 + wc * 32 + n * 16 + lr;      // 0..3071
      const int which = col >> 10;                           // uniform per (bn,wc,n)
      #pragma unroll
      for (int j = 0; j < 4; ++j){
        const int row = bm * 128 + wr * 64 + m * 16 + lg * 4 + j;   // token 0..4095
        float v = acc[m][n][j];
        if (which == 2){
          Vq[(size_t)row * 1024 + (col - 2048)] = f2bf(v);
        } else {
          const int d  = col & 63;
          const int dp = d >> 1;
          const float c = tab[(size_t)row * 64 + dp];
          const float s = tab[(size_t)row * 64 + 32 + dp];
          const float p = __shfl_xor(v, 1);
          float r = v * c + p * ((d & 1) ? s : -s);
          if (which == 0) r *= 0.125f;                       // fold 1/sqrt(64) into Q
          short* dst = which ? Kr : Qr;
          const int b = row >> 11, si = row & 2047;
          const int h = (col >> 6) & 15;
          dst[(((size_t)(b * NH + h)) * S_ + si) * DK + d] = f2bf(r);
        }
      }
    }
}

// ---------------- 8-wave bf16 GEMM: C = A * B^T (for out-proj) ----------------
template<typename OutT>
__launch_bounds__(512)
__global__ void gemm_bt8(const short* __restrict__ A, const short* __restrict__ Bm,
                         OutT* __restrict__ C, int M, int N, int K){
  __shared__ short As[128 * 32];
  __shared__ short Bs[128 * 32];
  const int tid = threadIdx.x;
  const int l = tid & 63, w = tid >> 6;
  const int lr = l & 15, lg = l >> 4;
  const int wr = w >> 2, wc = w & 3;
  const int nwg = gridDim.x * gridDim.y;
  const int wg  = blockIdx.y * gridDim.x + blockIdx.x;
  const int sw  = (wg & 7) * (nwg >> 3) + (wg >> 3);
  const int bn  = sw % gridDim.x, bm = sw / gridDim.x;
  const short* Ab = A + (size_t)bm * 128 * K;
  const short* Bb = Bm + (size_t)bn * 128 * K;
  f32x4 acc[4][2];
  #pragma unroll
  for (int m = 0; m < 4; ++m)
    #pragma unroll
    for (int n = 0; n < 2; ++n) acc[m][n] = (f32x4){0.f, 0.f, 0.f, 0.f};
  const int r0 = tid >> 2, q4 = tid & 3;
  for (int kt = 0; kt < K; kt += 32){
    gload16(Ab + (size_t)r0 * K + kt + q4 * 8, As + tid * 8);
    gload16(Bb + (size_t)r0 * K + kt + q4 * 8, Bs + tid * 8);
    __syncthreads();
    bf16x8 a[4], bfr[2];
    #pragma unroll
    for (int m = 0; m < 4; ++m)
      a[m] = *(const bf16x8*)(As + (wr * 64 + m * 16 + lr) * 32 + lg * 8);
    #pragma unroll
    for (int n = 0; n < 2; ++n)
      bfr[n] = *(const bf16x8*)(Bs + (wc * 32 + n * 16 + lr) * 32 + lg * 8);
    #pragma unroll
    for (int m = 0; m < 4; ++m)
      #pragma unroll
      for (int n = 0; n < 2; ++n)
        acc[m][n] = __builtin_amdgcn_mfma_f32_16x16x32_bf16(a[m], bfr[n], acc[m][n], 0, 0, 0);
    __syncthreads();
  }
  #pragma unroll
  for (int m = 0; m < 4; ++m)
    #pragma unroll
    for (int n = 0; n < 2; ++n)
      #pragma unroll
      for (int j = 0; j < 4; ++j){
        int row = bm * 128 + wr * 64 + m * 16 + lg * 4 + j;
        int col = bn * 128 + wc * 32 + n * 16 + lr;
        float v = acc[m][n][j];
        if constexpr (__is_same(OutT, short)) C[(size_t)row * N + col] = f2bf(v);
        else                                  C[(size_t)row * N + col] = v;
      }
}

// ---------------- V transpose: Vq [b,s,h,d] -> Vt [b,h,d,s] bf16 ----------------
__global__ void vtrans(const short* __restrict__ Vq, short* __restrict__ Vt){
  __shared__ short t[64][72];
  const int tid = threadIdx.x;
  const int st = blockIdx.x, bh = blockIdx.y;
  const int b = bh >> 4, h = bh & 15;
  #pragma unroll
  for (int i = 0; i < 2; ++i){
    int c = tid + 256 * i;
    int sl = c >> 3, d8 = c & 7;
    const short* src = Vq + ((size_t)b * S_ + st * 64 + sl) * 1024 + h * 64 + d8 * 8;
    *(bf16x8*)(&t[sl][d8 * 8]) = *(const bf16x8*)src;
  }
  __syncthreads();
  #pragma unroll
  for (int i = 0; i < 2; ++i){
    int c = tid + 256 * i;
    int dl = c >> 3, s8 = c & 7;
    bf16x8 v;
    #pragma unroll
    for (int jj = 0; jj < 8; ++jj) v[jj] = t[s8 * 8 + jj][dl];
    short* dst = Vt + ((size_t)bh * DK + dl) * S_ + st * 64 + s8 * 8;
    *(bf16x8*)dst = v;
  }
}

// ---------------- per-Q-tile step: swapped QK^T, in-register row softmax, defer-max ----------------
// Ks/Vs XOR-swizzled [64 rows][8 x 16B chunks]: global chunk c of row r at slot c ^ (r&7).
// Pw: per-wave [16 rows][32 u32] of packed bf16 P pairs, col swizzled by ((lr&7)<<2).
__device__ __forceinline__ void attn_tile_step(
    const bf16x8 qa0, const bf16x8 qa1,
    f32x4 (&acc)[4], float& mrow, float& lsum,
    const short* Ks, const short* Vs, unsigned* pw,
    int diagmask, int lr, int lg, int wl){
  float sv[4][4];
  #pragma unroll
  for (int n = 0; n < 4; ++n){
    const int R = n * 16 + lr;
    const int c0 = lg ^ (R & 7);
    bf16x8 k0 = *(const bf16x8*)(Ks + R * 64 + c0 * 8);
    bf16x8 k1 = *(const bf16x8*)(Ks + R * 64 + (c0 ^ 4) * 8);
    f32x4 z = (f32x4){0.f, 0.f, 0.f, 0.f};
    z = __builtin_amdgcn_mfma_f32_16x16x32_bf16(k0, qa0, z, 0, 0, 0);   // S^T tile
    z = __builtin_amdgcn_mfma_f32_16x16x32_bf16(k1, qa1, z, 0, 0, 0);
    #pragma unroll
    for (int j = 0; j < 4; ++j) sv[n][j] = z[j];   // sv[n][j] = S[q=wl*16+lr][k=n*16+lg*4+j]
  }
  if (diagmask){
    const int qloc = wl * 16 + lr;
    #pragma unroll
    for (int n = 0; n < 4; ++n)
      #pragma unroll
      for (int j = 0; j < 4; ++j)
        if (n * 16 + lg * 4 + j > qloc) sv[n][j] = -1e30f;
  }
  // row softmax: lane owns one q-row; combine over lg groups (xor 16, 32)
  float lm = sv[0][0];
  #pragma unroll
  for (int n = 0; n < 4; ++n)
    #pragma unroll
    for (int j = 0; j < 4; ++j) lm = fmaxf(lm, sv[n][j]);
  lm = fmaxf(lm, __shfl_xor(lm, 16));
  lm = fmaxf(lm, __shfl_xor(lm, 32));
  // defer-max (T13): skip rescale while tile max stays within +8 of running max
  if (!__all(lm <= mrow + 8.f)){
    float mnew = fmaxf(mrow, lm);
    float corr = __expf(mrow - mnew);
    mrow = mnew;
    lsum *= corr;
    float cb[4];
    #pragma unroll
    for (int j = 0; j < 4; ++j) cb[j] = __shfl(corr, lg * 4 + j);
    #pragma unroll
    for (int n = 0; n < 4; ++n)
      #pragma unroll
      for (int j = 0; j < 4; ++j) acc[n][j] *= cb[j];
  }
  float psum = 0.f;
  #pragma unroll
  for (int n = 0; n < 4; ++n)
    #pragma unroll
    for (int j = 0; j < 4; ++j){
      float p = __expf(sv[n][j] - mrow);
      sv[n][j] = p; psum += p;
    }
  psum += __shfl_xor(psum, 16);
  psum += __shfl_xor(psum, 32);
  lsum += psum;
  // pack P (bf16 pairs) -> per-wave LDS, reread as PV A-fragments (row-local, swizzled)
  const int swz = (lr & 7) << 2;
  #pragma unroll
  for (int n = 0; n < 4; ++n){
    pw[lr * 32 + ((n * 8 + lg * 2 + 0) ^ swz)] = packbf(sv[n][0], sv[n][1]);
    pw[lr * 32 + ((n * 8 + lg * 2 + 1) ^ swz)] = packbf(sv[n][2], sv[n][3]);
  }
  bf16x8 pa0 = *(const bf16x8*)(pw + lr * 32 + ((lg * 4) ^ swz));        // k 0..31
  bf16x8 pa1 = *(const bf16x8*)(pw + lr * 32 + ((16 + lg * 4) ^ swz));   // k 32..63
  #pragma unroll
  for (int n = 0; n < 4; ++n){
    const int R = n * 16 + lr;
    const int c0 = lg ^ (R & 7);
    bf16x8 v0 = *(const bf16x8*)(Vs + R * 64 + c0 * 8);
    bf16x8 v1 = *(const bf16x8*)(Vs + R * 64 + (c0 ^ 4) * 8);
    acc[n] = __builtin_amdgcn_mfma_f32_16x16x32_bf16(pa0, v0, acc[n], 0, 0, 0);
    acc[n] = __builtin_amdgcn_mfma_f32_16x16x32_bf16(pa1, v1, acc[n], 0, 0, 0);
  }
}

// ---------------- flash attention: paired Q-tiles (qt, 31-qt) on separate wave-groups ----------------
// 512 threads: waves 0-3 own tile t1 = 31-qp, waves 4-7 own tile t0 = qp. Shared K/V staging.
__launch_bounds__(512)
__global__ void attn_kernel(const short* __restrict__ Qr, const short* __restrict__ Kr,
                            const short* __restrict__ Vt, short* __restrict__ AO){
  __shared__ short Ks[2][64 * 64];
  __shared__ short Vs[2][64 * 64];   // [d][kk]
  __shared__ unsigned Pw[8][16 * 32];
  const int tid = threadIdx.x;
  const int l = tid & 63, w = tid >> 6;
  const int lr = l & 15, lg = l >> 4;
  const int wl = w & 3, wgp = w >> 2;
  const int qp = blockIdx.x, h = blockIdx.y, b = blockIdx.z;
  const int t0 = qp, t1 = 31 - qp;           // t0 in 0..15, t1 in 16..31
  const int myqt = wgp ? t0 : t1;
  const int bh = b * NH + h;
  const short* Qp = Qr + (size_t)bh * S_ * DK;
  const short* Kp = Kr + (size_t)bh * S_ * DK;
  const short* Vp = Vt + (size_t)bh * DK * S_;

  bf16x8 qa0, qa1;
  {
    const short* q0 = Qp + (size_t)(myqt * 64 + wl * 16 + lr) * DK + lg * 8;
    qa0 = *(const bf16x8*)q0; qa1 = *(const bf16x8*)(q0 + 32);
  }
  f32x4 acc[4];
  float ms = -1e30f, ls = 0.f;
  #pragma unroll
  for (int n = 0; n < 4; ++n) acc[n] = (f32x4){0.f, 0.f, 0.f, 0.f};
  unsigned* pw = &Pw[w][0];
  const int r0 = tid >> 3, q8 = tid & 7;          // staging: [64 rows][8 x 16B chunks], 512 threads
  const int sq8 = q8 ^ (r0 & 7);                  // pre-swizzled source chunk (rule #21)

  // prologue: stage tile 0 into buffer 0
  gload16(Kp + (size_t)r0 * DK + sq8 * 8, &Ks[0][tid * 8]);
  gload16(Vp + (size_t)r0 * S_ + sq8 * 8, &Vs[0][tid * 8]);
  int cur = 0;
  for (int kt = 0; kt <= t1; ++kt){
    __syncthreads();   // drains vmcnt: buf[cur] ready; all waves done reading buf[cur^1]
    if (kt < t1){
      gload16(Kp + (size_t)((kt + 1) * 64 + r0) * DK + sq8 * 8, &Ks[cur ^ 1][tid * 8]);
      gload16(Vp + (size_t)r0 * S_ + (kt + 1) * 64 + sq8 * 8,   &Vs[cur ^ 1][tid * 8]);
    }
    if (kt <= myqt)
      attn_tile_step(qa0, qa1, acc, ms, ls, Ks[cur], Vs[cur], pw, kt == myqt, lr, lg, wl);
    cur ^= 1;
  }
  const float li = 1.f / ls;
  #pragma unroll
  for (int j = 0; j < 4; ++j){
    const float d0 = __shfl(li, lg * 4 + j);
    #pragma unroll
    for (int n = 0; n < 4; ++n){
      int e = h * 64 + n * 16 + lr;
      int r = myqt * 64 + wl * 16 + lg * 4 + j;
      AO[((size_t)b * S_ + r) * DM + e] = f2bf(acc[n][j] * d0);
    }
  }
}

extern "C" void kernel_launch(void* const* d_in, const int* in_sizes, int n_in,
                              void* d_out, int out_size, void* d_ws, size_t ws_size,
                              hipStream_t stream){
  const float* x  = (const float*)d_in[0];
  const float* wq = (const float*)d_in[1];
  const float* wk = (const float*)d_in[2];
  const float* wv = (const float*)d_in[3];
  const float* wo = (const float*)d_in[4];
  const int*  pos = (const int*)d_in[5];

  char* ws = (char*)d_ws;
  short* xb   = (short*)(ws + 0);                       // 8 MB  [4096][1024] bf16 x
  short* wqkv = (short*)(ws + ((size_t)8  << 20));      // 6 MB  [3072][1024] bf16 (wq|wk|wv)
  short* wob  = (short*)(ws + ((size_t)14 << 20));      // 2 MB  [1024][1024]
  short* Vq   = (short*)(ws + ((size_t)16 << 20));      // 8 MB  [b,s,h,d] V raw
  short* Qr   = (short*)(ws + ((size_t)40 << 20));      // 8 MB  [b,h,s,d]
  short* Kr   = (short*)(ws + ((size_t)48 << 20));      // 8 MB  [b,h,s,d]
  short* Vt   = (short*)(ws + ((size_t)56 << 20));      // 8 MB  [b,h,d,s]
  float* tab  = (float*)(ws + ((size_t)64 << 20));      // 1 MB  rope table
  short* AO   = xb;                                     // reuse xb (dead after GEMM1)
  float* out  = (float*)d_out;

  rope_table<<<dim3((B_ * S_ * 32 + 255) / 256), dim3(256), 0, stream>>>(pos, tab);
  cast_all<<<dim3(8192), dim3(256), 0, stream>>>(x, wq, wk, wv, wo, xb, wqkv, wob);
  gemm_qkv<<<dim3(24, 32), dim3(512), 0, stream>>>(xb, wqkv, tab, Qr, Kr, Vq, 1024);
  vtrans<<<dim3(32, 32), dim3(256), 0, stream>>>(Vq, Vt);
  attn_kernel<<<dim3(16, NH, B_), dim3(512), 0, stream>>>(Qr, Kr, Vt, AO);
  gemm_bt8<float><<<dim3(8, 32), dim3(512), 0, stream>>>(AO, wob, out, 4096, 1024, 1024);
}